// Round 7
// baseline (562.154 us; speedup 1.0000x reference)
//
#include <hip/hip_runtime.h>

#define NRELS 8

typedef __attribute__((ext_vector_type(8))) short short8;
typedef __attribute__((ext_vector_type(4))) float f32x4;

__device__ __forceinline__ unsigned short f2bf(float f) {
  unsigned int u = __float_as_uint(f);
  u += 0x7FFFu + ((u >> 16) & 1u);
  return (unsigned short)(u >> 16);
}
__device__ __forceinline__ float bf2f(unsigned short h) {
  return __uint_as_float(((unsigned int)h) << 16);
}

__device__ __forceinline__ void gload_lds16(const void* g, void* l) {
  __builtin_amdgcn_global_load_lds(
      (const __attribute__((address_space(1))) unsigned int*)g,
      (__attribute__((address_space(3))) unsigned int*)l, 16, 0, 0);
}

// ---------------- histogram over (dst,rel) keys ----------------

__global__ __launch_bounds__(256) void hist_kernel(
    const int* __restrict__ dstp, const int* __restrict__ et, int E,
    int* __restrict__ hist) {
  int i = blockIdx.x * blockDim.x + threadIdx.x;
  if (i < E) {
    atomicAdd(&hist[(size_t)dstp[i] * NRELS + et[i]], 1);
  }
}

// ---------------- hierarchical exclusive scan over M = 8N keys ----------------

__global__ __launch_bounds__(256) void scan1_kernel(
    const int* __restrict__ hist, int M, int* __restrict__ row_off,
    int* __restrict__ bsum) {
  __shared__ int s[256];
  int t = threadIdx.x;
  int i = blockIdx.x * 256 + t;
  int v = (i < M) ? hist[i] : 0;
  s[t] = v;
  __syncthreads();
  for (int off = 1; off < 256; off <<= 1) {
    int u = (t >= off) ? s[t - off] : 0;
    __syncthreads();
    s[t] += u;
    __syncthreads();
  }
  if (i < M) row_off[i] = s[t] - v;  // local exclusive
  if (t == 255) bsum[blockIdx.x] = s[255];
}

__global__ __launch_bounds__(256) void scan2_kernel(int* __restrict__ bsum, int NB) {
  __shared__ int s[256];
  int t = threadIdx.x;
  int C = (NB + 255) / 256;
  int b0 = t * C, b1 = min(NB, b0 + C);
  int sum = 0;
  for (int i = b0; i < b1; i++) sum += bsum[i];
  s[t] = sum;
  __syncthreads();
  for (int off = 1; off < 256; off <<= 1) {
    int u = (t >= off) ? s[t - off] : 0;
    __syncthreads();
    s[t] += u;
    __syncthreads();
  }
  int base = (t == 0) ? 0 : s[t - 1];
  for (int i = b0; i < b1; i++) {
    int v = bsum[i];
    bsum[i] = base;
    base += v;
  }
  if (t == 255) bsum[NB] = s[255];
}

__global__ __launch_bounds__(256) void scan3_kernel(
    int* __restrict__ row_off, int* __restrict__ cursor,
    const int* __restrict__ bsum, int M, int NB) {
  int i = blockIdx.x * 256 + threadIdx.x;
  if (i < M) {
    int v = row_off[i] + bsum[i >> 8];
    row_off[i] = v;
    cursor[i] = v;
  } else if (i == M) {
    row_off[M] = bsum[NB];
  }
}

// ---------------- bucket edges by (dst,rel); store src ----------------

__global__ __launch_bounds__(256) void bucket_kernel(
    const int* __restrict__ src, const int* __restrict__ dstp,
    const int* __restrict__ et, int E, int* __restrict__ cursor,
    int* __restrict__ epack) {
  int i = blockIdx.x * blockDim.x + threadIdx.x;
  if (i < E) {
    int pos = atomicAdd(&cursor[(size_t)dstp[i] * NRELS + et[i]], 1);
    epack[pos] = src[i];
  }
}

// ---------------- fp32 -> bf16 feature conversion ----------------

__global__ __launch_bounds__(256) void cvt_x_kernel(
    const float* __restrict__ x, unsigned short* __restrict__ xb, int n4) {
  int i = blockIdx.x * blockDim.x + threadIdx.x;
  if (i < n4) {
    float4 v = ((const float4*)x)[i];
    ushort4 o;
    o.x = f2bf(v.x); o.y = f2bf(v.y); o.z = f2bf(v.z); o.w = f2bf(v.w);
    ((ushort4*)xb)[i] = o;
  }
}

// ---------------- weights -> bf16, transposed to [n][k] with k = [8*128 | 128] ------

__global__ __launch_bounds__(256) void cvt_w_kernel(
    const float* __restrict__ W1, const float* __restrict__ root1,
    const float* __restrict__ W2, const float* __restrict__ root2,
    unsigned short* __restrict__ Wt1, unsigned short* __restrict__ Wt2) {
  int idx = blockIdx.x * blockDim.x + threadIdx.x;
  const int T1 = 128 * 1152;
  const int T2 = 64 * 1152;
  if (idx < T1) {
    int n = idx / 1152, k = idx % 1152;
    float v = (k < 1024) ? W1[(size_t)k * 128 + n] : root1[(size_t)(k - 1024) * 128 + n];
    Wt1[idx] = f2bf(v);
  } else if (idx < T1 + T2) {
    int j = idx - T1;
    int n = j / 1152, k = j % 1152;
    float v = (k < 1024) ? W2[(size_t)k * 64 + n] : root2[(size_t)(k - 1024) * 64 + n];
    Wt2[j] = f2bf(v);
  }
}

// ---------------- fused gather-aggregate + MFMA GEMM ----------------
// C[N,BN] = [agg(feat) | feat] @ Bt[BN,1152]^T + bias
// Per 64-row block: for r in 0..8 (8 relations + own features), gather the
// relation's K=128 slice into LDS A-tile (fp32 accum -> bf16), stage B slice
// via global_load_lds, run 4 MFMA k-steps.  No Abig round-trip.
// LDS rows stride 256B; XOR swizzle byte ^= (row&7)<<4 on both write and read.

template <int BN, bool RELU_BF16_OUT>
__global__ __launch_bounds__(256) void gemm_fused(
    const unsigned short* __restrict__ feat,  // [N][128] bf16
    const int* __restrict__ row_off,          // [8N+1]
    const int* __restrict__ epack,            // [E] src ids (dst,rel)-sorted
    const unsigned short* __restrict__ Bt,    // [BN][1152] bf16
    const float* __restrict__ bias,           // [BN] fp32
    void* __restrict__ Cout, int N) {
  constexpr int K = 1152;
  constexpr int FM = 2;
  constexpr int FN = BN / 32;  // 4 (BN=128) or 2 (BN=64)

  __shared__ unsigned short As[64 * 128];   // 16 KB
  __shared__ unsigned short Bs[BN * 128];   // 32/16 KB

  const int tid = threadIdx.x;
  const int lane = tid & 63;
  const int wid = tid >> 6;
  const int wm = wid >> 1, wn = wid & 1;
  const int l15 = lane & 15, lhi = lane >> 4;
  const int bm0 = blockIdx.x * 64;

  f32x4 acc[FM][FN];
#pragma unroll
  for (int i = 0; i < FM; i++)
#pragma unroll
    for (int j = 0; j < FN; j++) acc[i][j] = (f32x4){0.f, 0.f, 0.f, 0.f};

  for (int r = 0; r < 9; r++) {
    if (r) __syncthreads();  // protect LDS against overwrite while prev compute reads

    // ---- stage A: 16 rows per wave, full relation-r K-slice (128 cols)
    for (int rr = 0; rr < 16; rr++) {
      int row = wid * 16 + rr;
      int grow = bm0 + row;
      unsigned int oval = 0;
      if (grow < N) {
        if (r < 8) {
          int b = row_off[(size_t)grow * NRELS + r];
          int e = row_off[(size_t)grow * NRELS + r + 1];
          float a0 = 0.f, a1 = 0.f;
          for (int i = b; i < e; i++) {
            int s = epack[i];
            unsigned int pv = *(const unsigned int*)(feat + (size_t)s * 128 + lane * 2);
            a0 += bf2f((unsigned short)(pv & 0xFFFF));
            a1 += bf2f((unsigned short)(pv >> 16));
          }
          float nrm = 1.0f / (float)max(e - b, 1);
          oval = (unsigned int)f2bf(a0 * nrm) | ((unsigned int)f2bf(a1 * nrm) << 16);
        } else {
          oval = *(const unsigned int*)(feat + (size_t)grow * 128 + lane * 2);
        }
      }
      *(unsigned int*)((char*)As + row * 256 + ((lane * 4) ^ ((row & 7) << 4))) = oval;
    }

    // ---- stage B: BN rows x 128 cols of slice r (pre-swizzled source)
#pragma unroll
    for (int c = 0; c < BN / 16; c++) {
      int o = c * 4096 + tid * 16;
      int n = o >> 8;
      int colb = o & 255;
      int scol = (colb ^ ((n & 7) << 4)) >> 1;  // element offset
      gload_lds16(Bt + (size_t)n * K + r * 128 + scol, (char*)Bs + o);
    }
    asm volatile("s_waitcnt vmcnt(0)" ::: "memory");
    __syncthreads();

    // ---- compute: 4 k-steps of 32
#pragma unroll
    for (int ks = 0; ks < 4; ks++) {
      short8 af[FM], bf[FN];
#pragma unroll
      for (int fm = 0; fm < FM; fm++) {
        int row = wm * 32 + fm * 16 + l15;
        af[fm] = *(const short8*)((const char*)As + row * 256 +
                                  ((ks * 64 + lhi * 16) ^ ((row & 7) << 4)));
      }
#pragma unroll
      for (int fn = 0; fn < FN; fn++) {
        int n = wn * (BN / 2) + fn * 16 + l15;
        bf[fn] = *(const short8*)((const char*)Bs + n * 256 +
                                  ((ks * 64 + lhi * 16) ^ ((n & 7) << 4)));
      }
#pragma unroll
      for (int fm = 0; fm < FM; fm++)
#pragma unroll
        for (int fn = 0; fn < FN; fn++)
          acc[fm][fn] = __builtin_amdgcn_mfma_f32_16x16x32_bf16(
              af[fm], bf[fn], acc[fm][fn], 0, 0, 0);
    }
  }

  // ---- epilogue
#pragma unroll
  for (int fm = 0; fm < FM; fm++) {
#pragma unroll
    for (int fn = 0; fn < FN; fn++) {
      int col = wn * (BN / 2) + fn * 16 + l15;
      float bcol = bias[col];
#pragma unroll
      for (int i = 0; i < 4; i++) {
        int row = bm0 + wm * 32 + fm * 16 + lhi * 4 + i;
        if (row < N) {
          float v = acc[fm][fn][i] + bcol;
          if (RELU_BF16_OUT) {
            ((unsigned short*)Cout)[(size_t)row * BN + col] = f2bf(fmaxf(v, 0.f));
          } else {
            ((float*)Cout)[(size_t)row * BN + col] = v;
          }
        }
      }
    }
  }
}

// ---------------- launch ----------------

extern "C" void kernel_launch(void* const* d_in, const int* in_sizes, int n_in,
                              void* d_out, int out_size, void* d_ws, size_t ws_size,
                              hipStream_t stream) {
  const float* x     = (const float*)d_in[0];
  const int*   eidx  = (const int*)d_in[1];
  const int*   et    = (const int*)d_in[2];
  const float* W1    = (const float*)d_in[3];
  const float* root1 = (const float*)d_in[4];
  const float* b1    = (const float*)d_in[5];
  const float* W2    = (const float*)d_in[6];
  const float* root2 = (const float*)d_in[7];
  const float* b2    = (const float*)d_in[8];
  float* out = (float*)d_out;

  const int IN = 128;
  const int N = in_sizes[0] / IN;
  const int E = in_sizes[2];
  const int* src = eidx;
  const int* dst = eidx + E;
  const int M = N * NRELS;            // (dst,rel) key space
  const int NB = (M + 255) / 256;

  auto align = [](size_t v) { return (v + 255) & ~(size_t)255; };
  char* base = (char*)d_ws;
  size_t o = 0;
  int* hist = (int*)(base + o);
  size_t zero_end = (size_t)M * 4;    // memset covers hist only
  o = align(zero_end);
  int* row_off = (int*)(base + o);
  o = align(o + (size_t)(M + 1) * 4);
  int* cursor = (int*)(base + o);
  o = align(o + (size_t)M * 4);
  int* bsum = (int*)(base + o);
  o = align(o + (size_t)(NB + 1) * 4);
  int* epack = (int*)(base + o);
  o = align(o + (size_t)E * 4);
  unsigned short* xb = (unsigned short*)(base + o);       // [N][128] bf16
  o = align(o + (size_t)N * 128 * 2);
  unsigned short* hrelu = (unsigned short*)(base + o);    // [N][128] bf16
  o = align(o + (size_t)N * 128 * 2);
  unsigned short* Wt1 = (unsigned short*)(base + o);      // [128][1152]
  o = align(o + (size_t)128 * 1152 * 2);
  unsigned short* Wt2 = (unsigned short*)(base + o);      // [64][1152]

  hipMemsetAsync(hist, 0, zero_end, stream);

  const int tb = 256;
  hist_kernel<<<(E + tb - 1) / tb, tb, 0, stream>>>(dst, et, E, hist);
  scan1_kernel<<<NB, 256, 0, stream>>>(hist, M, row_off, bsum);
  scan2_kernel<<<1, 256, 0, stream>>>(bsum, NB);
  scan3_kernel<<<(M + 256) / 256, 256, 0, stream>>>(row_off, cursor, bsum, M, NB);
  bucket_kernel<<<(E + tb - 1) / tb, tb, 0, stream>>>(src, dst, et, E, cursor, epack);
  cvt_x_kernel<<<(N * 128 / 4 + tb - 1) / tb, tb, 0, stream>>>(x, xb, N * 128 / 4);
  cvt_w_kernel<<<(128 * 1152 + 64 * 1152 + tb - 1) / tb, tb, 0, stream>>>(
      W1, root1, W2, root2, Wt1, Wt2);

  const int gblocks = (N + 63) / 64;

  // layer 1: hrelu = bf16(relu([agg(xb)|xb] @ Wt1^T + b1))
  gemm_fused<128, true><<<gblocks, 256, 0, stream>>>(
      xb, row_off, epack, Wt1, b1, hrelu, N);

  // layer 2: out = [agg(hrelu)|hrelu] @ Wt2^T + b2 (fp32)
  gemm_fused<64, false><<<gblocks, 256, 0, stream>>>(
      hrelu, row_off, epack, Wt2, b2, out, N);
}

// Round 8
// 271.444 us; speedup vs baseline: 2.0710x; 2.0710x over previous
//
#include <hip/hip_runtime.h>

#define NRELS 8

typedef __attribute__((ext_vector_type(8))) short short8;
typedef __attribute__((ext_vector_type(4))) float f32x4;

__device__ __forceinline__ unsigned short f2bf(float f) {
  unsigned int u = __float_as_uint(f);
  u += 0x7FFFu + ((u >> 16) & 1u);
  return (unsigned short)(u >> 16);
}
__device__ __forceinline__ float bf2f(unsigned short h) {
  return __uint_as_float(((unsigned int)h) << 16);
}

__device__ __forceinline__ void gload_lds16(const void* g, void* l) {
  __builtin_amdgcn_global_load_lds(
      (const __attribute__((address_space(1))) unsigned int*)g,
      (__attribute__((address_space(3))) unsigned int*)l, 16, 0, 0);
}

// ---------------- histogram over (dst,rel) keys ----------------

__global__ __launch_bounds__(256) void hist_kernel(
    const int* __restrict__ dstp, const int* __restrict__ et, int E,
    int* __restrict__ hist) {
  int i = blockIdx.x * blockDim.x + threadIdx.x;
  if (i < E) {
    atomicAdd(&hist[(size_t)dstp[i] * NRELS + et[i]], 1);
  }
}

// ---------------- hierarchical exclusive scan over M = 8N keys ----------------

__global__ __launch_bounds__(256) void scan1_kernel(
    const int* __restrict__ hist, int M, int* __restrict__ row_off,
    int* __restrict__ bsum) {
  __shared__ int s[256];
  int t = threadIdx.x;
  int i = blockIdx.x * 256 + t;
  int v = (i < M) ? hist[i] : 0;
  s[t] = v;
  __syncthreads();
  for (int off = 1; off < 256; off <<= 1) {
    int u = (t >= off) ? s[t - off] : 0;
    __syncthreads();
    s[t] += u;
    __syncthreads();
  }
  if (i < M) row_off[i] = s[t] - v;  // local exclusive
  if (t == 255) bsum[blockIdx.x] = s[255];
}

__global__ __launch_bounds__(256) void scan2_kernel(int* __restrict__ bsum, int NB) {
  __shared__ int s[256];
  int t = threadIdx.x;
  int C = (NB + 255) / 256;
  int b0 = t * C, b1 = min(NB, b0 + C);
  int sum = 0;
  for (int i = b0; i < b1; i++) sum += bsum[i];
  s[t] = sum;
  __syncthreads();
  for (int off = 1; off < 256; off <<= 1) {
    int u = (t >= off) ? s[t - off] : 0;
    __syncthreads();
    s[t] += u;
    __syncthreads();
  }
  int base = (t == 0) ? 0 : s[t - 1];
  for (int i = b0; i < b1; i++) {
    int v = bsum[i];
    bsum[i] = base;
    base += v;
  }
  if (t == 255) bsum[NB] = s[255];
}

__global__ __launch_bounds__(256) void scan3_kernel(
    int* __restrict__ row_off, int* __restrict__ cursor,
    const int* __restrict__ bsum, int M, int NB) {
  int i = blockIdx.x * 256 + threadIdx.x;
  if (i < M) {
    int v = row_off[i] + bsum[i >> 8];
    row_off[i] = v;
    cursor[i] = v;
  } else if (i == M) {
    row_off[M] = bsum[NB];
  }
}

// ---------------- bucket edges by (dst,rel); store src ----------------

__global__ __launch_bounds__(256) void bucket_kernel(
    const int* __restrict__ src, const int* __restrict__ dstp,
    const int* __restrict__ et, int E, int* __restrict__ cursor,
    int* __restrict__ epack) {
  int i = blockIdx.x * blockDim.x + threadIdx.x;
  if (i < E) {
    int pos = atomicAdd(&cursor[(size_t)dstp[i] * NRELS + et[i]], 1);
    epack[pos] = src[i];
  }
}

// ---------------- fp32 -> bf16 feature conversion ----------------

__global__ __launch_bounds__(256) void cvt_x_kernel(
    const float* __restrict__ x, unsigned short* __restrict__ xb, int n4) {
  int i = blockIdx.x * blockDim.x + threadIdx.x;
  if (i < n4) {
    float4 v = ((const float4*)x)[i];
    ushort4 o;
    o.x = f2bf(v.x); o.y = f2bf(v.y); o.z = f2bf(v.z); o.w = f2bf(v.w);
    ((ushort4*)xb)[i] = o;
  }
}

// ---------------- weights -> bf16, transposed to [n][k] with k = [8*128 | 128] ------

__global__ __launch_bounds__(256) void cvt_w_kernel(
    const float* __restrict__ W1, const float* __restrict__ root1,
    const float* __restrict__ W2, const float* __restrict__ root2,
    unsigned short* __restrict__ Wt1, unsigned short* __restrict__ Wt2) {
  int idx = blockIdx.x * blockDim.x + threadIdx.x;
  const int T1 = 128 * 1152;
  const int T2 = 64 * 1152;
  if (idx < T1) {
    int n = idx / 1152, k = idx % 1152;
    float v = (k < 1024) ? W1[(size_t)k * 128 + n] : root1[(size_t)(k - 1024) * 128 + n];
    Wt1[idx] = f2bf(v);
  } else if (idx < T1 + T2) {
    int j = idx - T1;
    int n = j / 1152, k = j % 1152;
    float v = (k < 1024) ? W2[(size_t)k * 64 + n] : root2[(size_t)(k - 1024) * 64 + n];
    Wt2[j] = f2bf(v);
  }
}

// ---------------- aggregate: (dst,rel)-sorted segments -> Abig[N][1024] bf16 ----------
// one wave per dst node; nontemporal stores (keep feat L3-resident); x2 unroll

__global__ __launch_bounds__(256) void agg_kernel(
    const unsigned short* __restrict__ feat,  // [N][128] bf16
    const int* __restrict__ row_off,          // [8N+1]
    const int* __restrict__ epack,            // [E] src ids (dst,rel)-sorted
    unsigned short* __restrict__ Abig,        // [N][1024] bf16
    int N) {
  int wid = (int)((blockIdx.x * blockDim.x + threadIdx.x) >> 6);
  if (wid >= N) return;
  int lane = threadIdx.x & 63;
  int lo2 = lane * 2;
  size_t arow = (size_t)wid * 1024;
  int kbase = wid * NRELS;
  int b = row_off[kbase];
#pragma unroll
  for (int r = 0; r < NRELS; r++) {
    int e = row_off[kbase + r + 1];
    float a0 = 0.f, a1 = 0.f;
    int i = b;
    for (; i + 1 < e; i += 2) {
      int s0 = epack[i], s1 = epack[i + 1];
      unsigned int p0 = *(const unsigned int*)(feat + (size_t)s0 * 128 + lo2);
      unsigned int p1 = *(const unsigned int*)(feat + (size_t)s1 * 128 + lo2);
      a0 += bf2f((unsigned short)(p0 & 0xFFFF)) + bf2f((unsigned short)(p1 & 0xFFFF));
      a1 += bf2f((unsigned short)(p0 >> 16)) + bf2f((unsigned short)(p1 >> 16));
    }
    if (i < e) {
      int s = epack[i];
      unsigned int pv = *(const unsigned int*)(feat + (size_t)s * 128 + lo2);
      a0 += bf2f((unsigned short)(pv & 0xFFFF));
      a1 += bf2f((unsigned short)(pv >> 16));
    }
    float nrm = 1.0f / (float)max(e - b, 1);
    unsigned int o = (unsigned int)f2bf(a0 * nrm) |
                     ((unsigned int)f2bf(a1 * nrm) << 16);
    __builtin_nontemporal_store(o, (unsigned int*)(Abig + arow + r * 128 + lo2));
    b = e;
  }
}

// ---------------- MFMA GEMM: C[N,BN] = [Abig | feat] @ Bt[BN,1152]^T + bias ----------
// A K-slices [0,1024) come from Abig (stride 1024); [1024,1152) from feat (stride 128).

template <int BN, bool RELU_BF16_OUT>
__global__ __launch_bounds__(256) void gemm_mfma(
    const unsigned short* __restrict__ Abig,  // [N][1024] bf16
    const unsigned short* __restrict__ feat,  // [N][128] bf16
    const unsigned short* __restrict__ Bt,    // [BN][1152] bf16
    const float* __restrict__ bias,           // [BN] fp32
    void* __restrict__ Cout, int N) {
  constexpr int K = 1152;
  constexpr int BM = 64;
  constexpr int FM = 2;
  constexpr int FN = BN / 32;  // 4 (BN=128) or 2 (BN=64)

  __shared__ unsigned short As[BM * 64];  // 8 KB,  row stride 128 B
  __shared__ unsigned short Bs[BN * 64];  // 16/8 KB

  const int tid = threadIdx.x;
  const int lane = tid & 63;
  const int wid = tid >> 6;
  const int wm = wid >> 1, wn = wid & 1;
  const int l15 = lane & 15, lhi = lane >> 4;
  const int bm0 = blockIdx.x * BM;

  f32x4 acc[FM][FN];
#pragma unroll
  for (int i = 0; i < FM; i++)
#pragma unroll
    for (int j = 0; j < FN; j++) acc[i][j] = (f32x4){0.f, 0.f, 0.f, 0.f};

  int a_addr[2][FM], b_addr[2][FN];
#pragma unroll
  for (int fm = 0; fm < FM; fm++) {
    int row = wm * 32 + fm * 16 + l15;
#pragma unroll
    for (int ks = 0; ks < 2; ks++) {
      int colb = ks * 64 + lhi * 16;
      a_addr[ks][fm] = row * 128 + (colb ^ ((row & 7) << 4));
    }
  }
#pragma unroll
  for (int fn = 0; fn < FN; fn++) {
    int n = wn * (BN / 2) + fn * 16 + l15;
#pragma unroll
    for (int ks = 0; ks < 2; ks++) {
      int colb = ks * 64 + lhi * 16;
      b_addr[ks][fn] = n * 128 + (colb ^ ((n & 7) << 4));
    }
  }

  for (int kb = 0; kb < K; kb += 64) {
    if (kb) __syncthreads();
#pragma unroll
    for (int itr = 0; itr < BM / 32; itr++) {
      int o = itr * 4096 + wid * 1024 + lane * 16;
      int row = o >> 7;
      int scol = ((o & 127) ^ ((row & 7) << 4)) >> 1;
      int gr = bm0 + row;
      gr = gr < N ? gr : N - 1;
      const unsigned short* arow =
          (kb < 1024) ? (Abig + (size_t)gr * 1024 + kb)
                      : (feat + (size_t)gr * 128 + (kb - 1024));
      gload_lds16(arow + scol, (char*)As + itr * 4096 + wid * 1024);
    }
#pragma unroll
    for (int itr = 0; itr < BN / 32; itr++) {
      int o = itr * 4096 + wid * 1024 + lane * 16;
      int n = o >> 7;
      int scol = ((o & 127) ^ ((n & 7) << 4)) >> 1;
      gload_lds16(Bt + (size_t)n * K + kb + scol,
                  (char*)Bs + itr * 4096 + wid * 1024);
    }
    asm volatile("s_waitcnt vmcnt(0)" ::: "memory");
    __syncthreads();

#pragma unroll
    for (int ks = 0; ks < 2; ks++) {
      short8 af[FM], bf[FN];
#pragma unroll
      for (int fm = 0; fm < FM; fm++)
        af[fm] = *(const short8*)((const char*)As + a_addr[ks][fm]);
#pragma unroll
      for (int fn = 0; fn < FN; fn++)
        bf[fn] = *(const short8*)((const char*)Bs + b_addr[ks][fn]);
#pragma unroll
      for (int fm = 0; fm < FM; fm++)
#pragma unroll
        for (int fn = 0; fn < FN; fn++)
          acc[fm][fn] = __builtin_amdgcn_mfma_f32_16x16x32_bf16(
              af[fm], bf[fn], acc[fm][fn], 0, 0, 0);
    }
  }

#pragma unroll
  for (int fm = 0; fm < FM; fm++) {
#pragma unroll
    for (int fn = 0; fn < FN; fn++) {
      int col = wn * (BN / 2) + fn * 16 + l15;
      float bcol = bias[col];
#pragma unroll
      for (int i = 0; i < 4; i++) {
        int row = bm0 + wm * 32 + fm * 16 + lhi * 4 + i;
        if (row < N) {
          float v = acc[fm][fn][i] + bcol;
          if (RELU_BF16_OUT) {
            ((unsigned short*)Cout)[(size_t)row * BN + col] = f2bf(fmaxf(v, 0.f));
          } else {
            ((float*)Cout)[(size_t)row * BN + col] = v;
          }
        }
      }
    }
  }
}

// ---------------- launch ----------------

extern "C" void kernel_launch(void* const* d_in, const int* in_sizes, int n_in,
                              void* d_out, int out_size, void* d_ws, size_t ws_size,
                              hipStream_t stream) {
  const float* x     = (const float*)d_in[0];
  const int*   eidx  = (const int*)d_in[1];
  const int*   et    = (const int*)d_in[2];
  const float* W1    = (const float*)d_in[3];
  const float* root1 = (const float*)d_in[4];
  const float* b1    = (const float*)d_in[5];
  const float* W2    = (const float*)d_in[6];
  const float* root2 = (const float*)d_in[7];
  const float* b2    = (const float*)d_in[8];
  float* out = (float*)d_out;

  const int IN = 128;
  const int N = in_sizes[0] / IN;
  const int E = in_sizes[2];
  const int* src = eidx;
  const int* dst = eidx + E;
  const int M = N * NRELS;            // (dst,rel) key space
  const int NB = (M + 255) / 256;

  auto align = [](size_t v) { return (v + 255) & ~(size_t)255; };
  char* base = (char*)d_ws;
  size_t o = 0;
  int* hist = (int*)(base + o);
  size_t zero_end = (size_t)M * 4;    // memset covers hist only
  o = align(zero_end);
  int* row_off = (int*)(base + o);
  o = align(o + (size_t)(M + 1) * 4);
  int* cursor = (int*)(base + o);
  o = align(o + (size_t)M * 4);
  int* bsum = (int*)(base + o);
  o = align(o + (size_t)(NB + 1) * 4);
  int* epack = (int*)(base + o);
  o = align(o + (size_t)E * 4);
  unsigned short* xb = (unsigned short*)(base + o);       // [N][128] bf16
  o = align(o + (size_t)N * 128 * 2);
  unsigned short* hrelu = (unsigned short*)(base + o);    // [N][128] bf16
  o = align(o + (size_t)N * 128 * 2);
  unsigned short* Wt1 = (unsigned short*)(base + o);      // [128][1152]
  o = align(o + (size_t)128 * 1152 * 2);
  unsigned short* Wt2 = (unsigned short*)(base + o);      // [64][1152]
  o = align(o + (size_t)64 * 1152 * 2);
  unsigned short* Abig = (unsigned short*)(base + o);     // [N][1024] bf16

  hipMemsetAsync(hist, 0, zero_end, stream);

  const int tb = 256;
  hist_kernel<<<(E + tb - 1) / tb, tb, 0, stream>>>(dst, et, E, hist);
  scan1_kernel<<<NB, 256, 0, stream>>>(hist, M, row_off, bsum);
  scan2_kernel<<<1, 256, 0, stream>>>(bsum, NB);
  scan3_kernel<<<(M + 256) / 256, 256, 0, stream>>>(row_off, cursor, bsum, M, NB);
  bucket_kernel<<<(E + tb - 1) / tb, tb, 0, stream>>>(src, dst, et, E, cursor, epack);
  cvt_x_kernel<<<(N * 128 / 4 + tb - 1) / tb, tb, 0, stream>>>(x, xb, N * 128 / 4);
  cvt_w_kernel<<<(128 * 1152 + 64 * 1152 + tb - 1) / tb, tb, 0, stream>>>(
      W1, root1, W2, root2, Wt1, Wt2);

  const int agrid = (N + 3) / 4;
  const int gblocks = (N + 63) / 64;

  // layer 1: Abig = agg(xb) ; hrelu = bf16(relu([Abig|xb] @ Wt1^T + b1))
  agg_kernel<<<agrid, 256, 0, stream>>>(xb, row_off, epack, Abig, N);
  gemm_mfma<128, true><<<gblocks, 256, 0, stream>>>(Abig, xb, Wt1, b1, hrelu, N);

  // layer 2: Abig = agg(hrelu) ; out = [Abig|hrelu] @ Wt2^T + b2 (fp32)
  agg_kernel<<<agrid, 256, 0, stream>>>(hrelu, row_off, epack, Abig, N);
  gemm_mfma<64, false><<<gblocks, 256, 0, stream>>>(Abig, hrelu, Wt2, b2, out, N);
}

// Round 9
// 265.712 us; speedup vs baseline: 2.1156x; 1.0216x over previous
//
#include <hip/hip_runtime.h>

#define NRELS 8

typedef __attribute__((ext_vector_type(8))) short short8;
typedef __attribute__((ext_vector_type(4))) float f32x4;

__device__ __forceinline__ unsigned short f2bf(float f) {
  unsigned int u = __float_as_uint(f);
  u += 0x7FFFu + ((u >> 16) & 1u);
  return (unsigned short)(u >> 16);
}
__device__ __forceinline__ float bf2f(unsigned short h) {
  return __uint_as_float(((unsigned int)h) << 16);
}

__device__ __forceinline__ void gload_lds16(const void* g, void* l) {
  __builtin_amdgcn_global_load_lds(
      (const __attribute__((address_space(1))) unsigned int*)g,
      (__attribute__((address_space(3))) unsigned int*)l, 16, 0, 0);
}

// ---------------- histogram over (dst,rel) keys ----------------

__global__ __launch_bounds__(256) void hist_kernel(
    const int* __restrict__ dstp, const int* __restrict__ et, int E,
    int* __restrict__ hist) {
  int i = blockIdx.x * blockDim.x + threadIdx.x;
  if (i < E) {
    atomicAdd(&hist[(size_t)dstp[i] * NRELS + et[i]], 1);
  }
}

// ---------------- hierarchical exclusive scan over M = 8N keys ----------------

__global__ __launch_bounds__(256) void scan1_kernel(
    const int* __restrict__ hist, int M, int* __restrict__ row_off,
    int* __restrict__ bsum) {
  __shared__ int s[256];
  int t = threadIdx.x;
  int i = blockIdx.x * 256 + t;
  int v = (i < M) ? hist[i] : 0;
  s[t] = v;
  __syncthreads();
  for (int off = 1; off < 256; off <<= 1) {
    int u = (t >= off) ? s[t - off] : 0;
    __syncthreads();
    s[t] += u;
    __syncthreads();
  }
  if (i < M) row_off[i] = s[t] - v;  // local exclusive
  if (t == 255) bsum[blockIdx.x] = s[255];
}

__global__ __launch_bounds__(256) void scan2_kernel(int* __restrict__ bsum, int NB) {
  __shared__ int s[256];
  int t = threadIdx.x;
  int C = (NB + 255) / 256;
  int b0 = t * C, b1 = min(NB, b0 + C);
  int sum = 0;
  for (int i = b0; i < b1; i++) sum += bsum[i];
  s[t] = sum;
  __syncthreads();
  for (int off = 1; off < 256; off <<= 1) {
    int u = (t >= off) ? s[t - off] : 0;
    __syncthreads();
    s[t] += u;
    __syncthreads();
  }
  int base = (t == 0) ? 0 : s[t - 1];
  for (int i = b0; i < b1; i++) {
    int v = bsum[i];
    bsum[i] = base;
    base += v;
  }
  if (t == 255) bsum[NB] = s[255];
}

__global__ __launch_bounds__(256) void scan3_kernel(
    int* __restrict__ row_off, int* __restrict__ cursor,
    const int* __restrict__ bsum, int M, int NB) {
  int i = blockIdx.x * 256 + threadIdx.x;
  if (i < M) {
    int v = row_off[i] + bsum[i >> 8];
    row_off[i] = v;
    cursor[i] = v;
  } else if (i == M) {
    row_off[M] = bsum[NB];
  }
}

// ---------------- bucket edges by (dst,rel); store src ----------------

__global__ __launch_bounds__(256) void bucket_kernel(
    const int* __restrict__ src, const int* __restrict__ dstp,
    const int* __restrict__ et, int E, int* __restrict__ cursor,
    int* __restrict__ epack) {
  int i = blockIdx.x * blockDim.x + threadIdx.x;
  if (i < E) {
    int pos = atomicAdd(&cursor[(size_t)dstp[i] * NRELS + et[i]], 1);
    epack[pos] = src[i];
  }
}

// ---------------- fp32 -> bf16 feature conversion ----------------

__global__ __launch_bounds__(256) void cvt_x_kernel(
    const float* __restrict__ x, unsigned short* __restrict__ xb, int n4) {
  int i = blockIdx.x * blockDim.x + threadIdx.x;
  if (i < n4) {
    float4 v = ((const float4*)x)[i];
    ushort4 o;
    o.x = f2bf(v.x); o.y = f2bf(v.y); o.z = f2bf(v.z); o.w = f2bf(v.w);
    ((ushort4*)xb)[i] = o;
  }
}

// ---- weights -> bf16, transposed to Bt[n][k] (k contiguous, 128 wide) ----
// Bt1[1152][128]: n<1024 -> W1[r][k][c] (n=r*128+c); n>=1024 -> root1[k][n-1024]
// Bt2[ 576][128]: n< 512 -> W2[r][k][c] (n=r*64 +c); n>= 512 -> root2[k][n-512]

__global__ __launch_bounds__(256) void cvt_w_kernel(
    const float* __restrict__ W1, const float* __restrict__ root1,
    const float* __restrict__ W2, const float* __restrict__ root2,
    unsigned short* __restrict__ Bt1, unsigned short* __restrict__ Bt2) {
  int idx = blockIdx.x * blockDim.x + threadIdx.x;
  const int T1 = 1152 * 128;
  const int T2 = 576 * 128;
  if (idx < T1) {
    int n = idx >> 7, k = idx & 127;
    float v;
    if (n < 1024) {
      int r = n >> 7, c = n & 127;
      v = W1[((size_t)r * 128 + k) * 128 + c];
    } else {
      v = root1[(size_t)k * 128 + (n - 1024)];
    }
    Bt1[idx] = f2bf(v);
  } else if (idx < T1 + T2) {
    int j = idx - T1;
    int n = j >> 7, k = j & 127;
    float v;
    if (n < 512) {
      int r = n >> 6, c = n & 63;
      v = W2[((size_t)r * 128 + k) * 64 + c];
    } else {
      v = root2[(size_t)k * 64 + (n - 512)];
    }
    Bt2[j] = f2bf(v);
  }
}

// ---------------- MFMA GEMM: xs[N,NC] = A[N,128] @ Bt[NC,128]^T (bf16 out) --------
// K=128 staged once; grid (row-tiles, NC/BN col-tiles). XOR swizzle as before.

template <int BN>
__global__ __launch_bounds__(256) void gemm_xs(
    const unsigned short* __restrict__ A,   // [N][128] bf16
    const unsigned short* __restrict__ Bt,  // [NC][128] bf16
    unsigned short* __restrict__ Cout,      // [N][NC] bf16
    int N, int NC) {
  constexpr int FM = 2;
  constexpr int FN = BN / 32;  // 4 (BN=128) or 2 (BN=64)

  __shared__ unsigned short As[64 * 128];   // 16 KB, 256B rows
  __shared__ unsigned short Bs[BN * 128];   // 32/16 KB

  const int tid = threadIdx.x;
  const int lane = tid & 63;
  const int wid = tid >> 6;
  const int wm = wid >> 1, wn = wid & 1;
  const int l15 = lane & 15, lhi = lane >> 4;
  const int bm0 = blockIdx.x * 64;
  const int n0 = blockIdx.y * BN;

  // stage A: 64 rows x 256 B (full K)
#pragma unroll
  for (int c = 0; c < 4; c++) {
    int o = c * 4096 + tid * 16;
    int row = o >> 8;
    int scol = ((o & 255) ^ ((row & 7) << 4)) >> 1;
    int gr = bm0 + row;
    gr = gr < N ? gr : N - 1;
    gload_lds16(A + (size_t)gr * 128 + scol, (char*)As + o);
  }
  // stage B: BN rows x 256 B
#pragma unroll
  for (int c = 0; c < BN / 16; c++) {
    int o = c * 4096 + tid * 16;
    int n = o >> 8;
    int scol = ((o & 255) ^ ((n & 7) << 4)) >> 1;
    gload_lds16(Bt + (size_t)(n0 + n) * 128 + scol, (char*)Bs + o);
  }
  asm volatile("s_waitcnt vmcnt(0)" ::: "memory");
  __syncthreads();

  f32x4 acc[FM][FN];
#pragma unroll
  for (int i = 0; i < FM; i++)
#pragma unroll
    for (int j = 0; j < FN; j++) acc[i][j] = (f32x4){0.f, 0.f, 0.f, 0.f};

#pragma unroll
  for (int ks = 0; ks < 4; ks++) {
    short8 af[FM], bf[FN];
#pragma unroll
    for (int fm = 0; fm < FM; fm++) {
      int row = wm * 32 + fm * 16 + l15;
      af[fm] = *(const short8*)((const char*)As + row * 256 +
                                ((ks * 64 + lhi * 16) ^ ((row & 7) << 4)));
    }
#pragma unroll
    for (int fn = 0; fn < FN; fn++) {
      int n = wn * (BN / 2) + fn * 16 + l15;
      bf[fn] = *(const short8*)((const char*)Bs + n * 256 +
                                ((ks * 64 + lhi * 16) ^ ((n & 7) << 4)));
    }
#pragma unroll
    for (int fm = 0; fm < FM; fm++)
#pragma unroll
      for (int fn = 0; fn < FN; fn++)
        acc[fm][fn] = __builtin_amdgcn_mfma_f32_16x16x32_bf16(
            af[fm], bf[fn], acc[fm][fn], 0, 0, 0);
  }

#pragma unroll
  for (int fm = 0; fm < FM; fm++) {
#pragma unroll
    for (int fn = 0; fn < FN; fn++) {
      int col = n0 + wn * (BN / 2) + fn * 16 + l15;
#pragma unroll
      for (int i = 0; i < 4; i++) {
        int row = bm0 + wm * 32 + fm * 16 + lhi * 4 + i;
        if (row < N) {
          Cout[(size_t)row * NC + col] = f2bf(acc[fm][fn][i]);
        }
      }
    }
  }
}

// ---------------- agg-finish layer 1: h = relu(sum_r mean_r(xs) + root + b1) -------
// one wave per node; lane handles 2 cols of 128; fp32 accumulation

__global__ __launch_bounds__(256) void agg_finish1(
    const unsigned short* __restrict__ xs,  // [N][1152] bf16
    const int* __restrict__ row_off,        // [8N+1]
    const int* __restrict__ epack,          // [E] src ids
    const float* __restrict__ b1,           // [128]
    unsigned short* __restrict__ h,         // [N][128] bf16 out (relu'd)
    int N) {
  int wid = (int)((blockIdx.x * blockDim.x + threadIdx.x) >> 6);
  if (wid >= N) return;
  int lane = threadIdx.x & 63;
  int lo2 = lane * 2;
  unsigned int own = *(const unsigned int*)(xs + (size_t)wid * 1152 + 1024 + lo2);
  float acc0 = bf2f((unsigned short)(own & 0xFFFF)) + b1[lo2];
  float acc1 = bf2f((unsigned short)(own >> 16)) + b1[lo2 + 1];
  int kbase = wid * NRELS;
  int b = row_off[kbase];
#pragma unroll
  for (int r = 0; r < NRELS; r++) {
    int e = row_off[kbase + r + 1];
    float a0 = 0.f, a1 = 0.f;
    int i = b;
    for (; i + 1 < e; i += 2) {
      int s0 = epack[i], s1 = epack[i + 1];
      unsigned int p0 = *(const unsigned int*)(xs + (size_t)s0 * 1152 + r * 128 + lo2);
      unsigned int p1 = *(const unsigned int*)(xs + (size_t)s1 * 1152 + r * 128 + lo2);
      a0 += bf2f((unsigned short)(p0 & 0xFFFF)) + bf2f((unsigned short)(p1 & 0xFFFF));
      a1 += bf2f((unsigned short)(p0 >> 16)) + bf2f((unsigned short)(p1 >> 16));
    }
    if (i < e) {
      int s = epack[i];
      unsigned int pv = *(const unsigned int*)(xs + (size_t)s * 1152 + r * 128 + lo2);
      a0 += bf2f((unsigned short)(pv & 0xFFFF));
      a1 += bf2f((unsigned short)(pv >> 16));
    }
    float nrm = 1.0f / (float)max(e - b, 1);
    acc0 += a0 * nrm;
    acc1 += a1 * nrm;
    b = e;
  }
  unsigned int o = (unsigned int)f2bf(fmaxf(acc0, 0.f)) |
                   ((unsigned int)f2bf(fmaxf(acc1, 0.f)) << 16);
  *(unsigned int*)(h + (size_t)wid * 128 + lo2) = o;
}

// ---------------- agg-finish layer 2: out = sum_r mean_r(ys) + root + b2 (fp32) ----
// one wave per node; lane handles 1 col of 64

__global__ __launch_bounds__(256) void agg_finish2(
    const unsigned short* __restrict__ ys,  // [N][576] bf16
    const int* __restrict__ row_off,        // [8N+1]
    const int* __restrict__ epack,          // [E] src ids
    const float* __restrict__ b2,           // [64]
    float* __restrict__ outp,               // [N][64] fp32
    int N) {
  int wid = (int)((blockIdx.x * blockDim.x + threadIdx.x) >> 6);
  if (wid >= N) return;
  int col = threadIdx.x & 63;
  float acc = bf2f(ys[(size_t)wid * 576 + 512 + col]) + b2[col];
  int kbase = wid * NRELS;
  int b = row_off[kbase];
#pragma unroll
  for (int r = 0; r < NRELS; r++) {
    int e = row_off[kbase + r + 1];
    float a0 = 0.f;
    int i = b;
    for (; i + 1 < e; i += 2) {
      int s0 = epack[i], s1 = epack[i + 1];
      a0 += bf2f(ys[(size_t)s0 * 576 + r * 64 + col]) +
            bf2f(ys[(size_t)s1 * 576 + r * 64 + col]);
    }
    if (i < e) {
      a0 += bf2f(ys[(size_t)epack[i] * 576 + r * 64 + col]);
    }
    acc += a0 / (float)max(e - b, 1);
    b = e;
  }
  outp[(size_t)wid * 64 + col] = acc;
}

// ---------------- launch ----------------

extern "C" void kernel_launch(void* const* d_in, const int* in_sizes, int n_in,
                              void* d_out, int out_size, void* d_ws, size_t ws_size,
                              hipStream_t stream) {
  const float* x     = (const float*)d_in[0];
  const int*   eidx  = (const int*)d_in[1];
  const int*   et    = (const int*)d_in[2];
  const float* W1    = (const float*)d_in[3];
  const float* root1 = (const float*)d_in[4];
  const float* b1    = (const float*)d_in[5];
  const float* W2    = (const float*)d_in[6];
  const float* root2 = (const float*)d_in[7];
  const float* b2    = (const float*)d_in[8];
  float* out = (float*)d_out;

  const int IN = 128;
  const int N = in_sizes[0] / IN;
  const int E = in_sizes[2];
  const int* src = eidx;
  const int* dst = eidx + E;
  const int M = N * NRELS;            // (dst,rel) key space
  const int NB = (M + 255) / 256;

  auto align = [](size_t v) { return (v + 255) & ~(size_t)255; };
  char* base = (char*)d_ws;
  size_t o = 0;
  int* hist = (int*)(base + o);
  size_t zero_end = (size_t)M * 4;    // memset covers hist only
  o = align(zero_end);
  int* row_off = (int*)(base + o);
  o = align(o + (size_t)(M + 1) * 4);
  int* cursor = (int*)(base + o);
  o = align(o + (size_t)M * 4);
  int* bsum = (int*)(base + o);
  o = align(o + (size_t)(NB + 1) * 4);
  int* epack = (int*)(base + o);
  o = align(o + (size_t)E * 4);
  unsigned short* xb = (unsigned short*)(base + o);       // [N][128] bf16
  o = align(o + (size_t)N * 128 * 2);
  unsigned short* hb = (unsigned short*)(base + o);       // [N][128] bf16 (relu'd h)
  o = align(o + (size_t)N * 128 * 2);
  unsigned short* Bt1 = (unsigned short*)(base + o);      // [1152][128]
  o = align(o + (size_t)1152 * 128 * 2);
  unsigned short* Bt2 = (unsigned short*)(base + o);      // [576][128]
  o = align(o + (size_t)576 * 128 * 2);
  unsigned short* xs = (unsigned short*)(base + o);       // [N][1152] bf16 (reused as ys [N][576])

  hipMemsetAsync(hist, 0, zero_end, stream);

  const int tb = 256;
  hist_kernel<<<(E + tb - 1) / tb, tb, 0, stream>>>(dst, et, E, hist);
  scan1_kernel<<<NB, 256, 0, stream>>>(hist, M, row_off, bsum);
  scan2_kernel<<<1, 256, 0, stream>>>(bsum, NB);
  scan3_kernel<<<(M + 256) / 256, 256, 0, stream>>>(row_off, cursor, bsum, M, NB);
  bucket_kernel<<<(E + tb - 1) / tb, tb, 0, stream>>>(src, dst, et, E, cursor, epack);
  cvt_x_kernel<<<(N * 128 / 4 + tb - 1) / tb, tb, 0, stream>>>(x, xb, N * 128 / 4);
  cvt_w_kernel<<<((1152 + 576) * 128 + tb - 1) / tb, tb, 0, stream>>>(
      W1, root1, W2, root2, Bt1, Bt2);

  const int agrid = (N + 3) / 4;
  const int gblocks = (N + 63) / 64;

  // layer 1: xs = xb @ Bt1^T ; h = relu(agg(xs) + root-slice + b1)
  {
    dim3 g(gblocks, 1152 / 128);
    gemm_xs<128><<<g, 256, 0, stream>>>(xb, Bt1, xs, N, 1152);
  }
  agg_finish1<<<agrid, 256, 0, stream>>>(xs, row_off, epack, b1, hb, N);

  // layer 2: ys = hb @ Bt2^T ; out = agg(ys) + root-slice + b2
  {
    dim3 g(gblocks, 576 / 64);
    gemm_xs<64><<<g, 256, 0, stream>>>(hb, Bt2, xs, N, 576);
  }
  agg_finish2<<<agrid, 256, 0, stream>>>(xs, row_off, epack, b2, out, N);
}

// Round 10
// 210.163 us; speedup vs baseline: 2.6748x; 1.2643x over previous
//
#include <hip/hip_runtime.h>

#define NRELS 8

typedef __attribute__((ext_vector_type(8))) short short8;
typedef __attribute__((ext_vector_type(4))) float f32x4;

__device__ __forceinline__ unsigned short f2bf(float f) {
  unsigned int u = __float_as_uint(f);
  u += 0x7FFFu + ((u >> 16) & 1u);
  return (unsigned short)(u >> 16);
}
__device__ __forceinline__ float bf2f(unsigned short h) {
  return __uint_as_float(((unsigned int)h) << 16);
}

__device__ __forceinline__ void gload_lds16(const void* g, void* l) {
  __builtin_amdgcn_global_load_lds(
      (const __attribute__((address_space(1))) unsigned int*)g,
      (__attribute__((address_space(3))) unsigned int*)l, 16, 0, 0);
}

// ---------------- histogram over (dst,rel) keys ----------------

__global__ __launch_bounds__(256) void hist_kernel(
    const int* __restrict__ dstp, const int* __restrict__ et, int E,
    int* __restrict__ hist) {
  int i = blockIdx.x * blockDim.x + threadIdx.x;
  if (i < E) {
    atomicAdd(&hist[(size_t)dstp[i] * NRELS + et[i]], 1);
  }
}

// ---------------- hierarchical exclusive scan over M = 8N keys + norm table -------

__global__ __launch_bounds__(256) void scan1_kernel(
    const int* __restrict__ hist, int M, int* __restrict__ row_off,
    int* __restrict__ bsum, float* __restrict__ nrm) {
  __shared__ int s[256];
  int t = threadIdx.x;
  int i = blockIdx.x * 256 + t;
  int v = (i < M) ? hist[i] : 0;
  if (i < M) nrm[i] = 1.0f / (float)max(v, 1);
  s[t] = v;
  __syncthreads();
  for (int off = 1; off < 256; off <<= 1) {
    int u = (t >= off) ? s[t - off] : 0;
    __syncthreads();
    s[t] += u;
    __syncthreads();
  }
  if (i < M) row_off[i] = s[t] - v;  // local exclusive
  if (t == 255) bsum[blockIdx.x] = s[255];
}

__global__ __launch_bounds__(256) void scan2_kernel(int* __restrict__ bsum, int NB) {
  __shared__ int s[256];
  int t = threadIdx.x;
  int C = (NB + 255) / 256;
  int b0 = t * C, b1 = min(NB, b0 + C);
  int sum = 0;
  for (int i = b0; i < b1; i++) sum += bsum[i];
  s[t] = sum;
  __syncthreads();
  for (int off = 1; off < 256; off <<= 1) {
    int u = (t >= off) ? s[t - off] : 0;
    __syncthreads();
    s[t] += u;
    __syncthreads();
  }
  int base = (t == 0) ? 0 : s[t - 1];
  for (int i = b0; i < b1; i++) {
    int v = bsum[i];
    bsum[i] = base;
    base += v;
  }
  if (t == 255) bsum[NB] = s[255];
}

__global__ __launch_bounds__(256) void scan3_kernel(
    int* __restrict__ row_off, int* __restrict__ cursor,
    const int* __restrict__ bsum, int M, int NB) {
  int i = blockIdx.x * 256 + threadIdx.x;
  if (i < M) {
    int v = row_off[i] + bsum[i >> 8];
    row_off[i] = v;
    cursor[i] = v;
  } else if (i == M) {
    row_off[M] = bsum[NB];
  }
}

// ---------------- bucket edges by (dst,rel); store src | rel<<20 ----------------

__global__ __launch_bounds__(256) void bucket_kernel(
    const int* __restrict__ src, const int* __restrict__ dstp,
    const int* __restrict__ et, int E, int* __restrict__ cursor,
    int* __restrict__ epack) {
  int i = blockIdx.x * blockDim.x + threadIdx.x;
  if (i < E) {
    int r = et[i];
    int pos = atomicAdd(&cursor[(size_t)dstp[i] * NRELS + r], 1);
    epack[pos] = src[i] | (r << 20);
  }
}

// ---------------- fp32 -> bf16 feature conversion ----------------

__global__ __launch_bounds__(256) void cvt_x_kernel(
    const float* __restrict__ x, unsigned short* __restrict__ xb, int n4) {
  int i = blockIdx.x * blockDim.x + threadIdx.x;
  if (i < n4) {
    float4 v = ((const float4*)x)[i];
    ushort4 o;
    o.x = f2bf(v.x); o.y = f2bf(v.y); o.z = f2bf(v.z); o.w = f2bf(v.w);
    ((ushort4*)xb)[i] = o;
  }
}

// ---- weights -> bf16, transposed to Bt[n][k] (k contiguous, 128 wide) ----

__global__ __launch_bounds__(256) void cvt_w_kernel(
    const float* __restrict__ W1, const float* __restrict__ root1,
    const float* __restrict__ W2, const float* __restrict__ root2,
    unsigned short* __restrict__ Bt1, unsigned short* __restrict__ Bt2) {
  int idx = blockIdx.x * blockDim.x + threadIdx.x;
  const int T1 = 1152 * 128;
  const int T2 = 576 * 128;
  if (idx < T1) {
    int n = idx >> 7, k = idx & 127;
    float v;
    if (n < 1024) {
      int r = n >> 7, c = n & 127;
      v = W1[((size_t)r * 128 + k) * 128 + c];
    } else {
      v = root1[(size_t)k * 128 + (n - 1024)];
    }
    Bt1[idx] = f2bf(v);
  } else if (idx < T1 + T2) {
    int j = idx - T1;
    int n = j >> 7, k = j & 127;
    float v;
    if (n < 512) {
      int r = n >> 6, c = n & 63;
      v = W2[((size_t)r * 128 + k) * 64 + c];
    } else {
      v = root2[(size_t)k * 64 + (n - 512)];
    }
    Bt2[j] = f2bf(v);
  }
}

// ---------------- MFMA GEMM: xs[N,NC] = A[N,128] @ Bt[NC,128]^T (bf16 out) --------
// grid (col-tiles, row-tiles): consecutive blocks share the A row-tile (L2-hot).

template <int BN>
__global__ __launch_bounds__(256) void gemm_xs(
    const unsigned short* __restrict__ A,   // [N][128] bf16
    const unsigned short* __restrict__ Bt,  // [NC][128] bf16
    unsigned short* __restrict__ Cout,      // [N][NC] bf16
    int N, int NC) {
  constexpr int FM = 2;
  constexpr int FN = BN / 32;  // 4 (BN=128) or 2 (BN=64)

  __shared__ unsigned short As[64 * 128];   // 16 KB, 256B rows
  __shared__ unsigned short Bs[BN * 128];   // 32/16 KB

  const int tid = threadIdx.x;
  const int lane = tid & 63;
  const int wid = tid >> 6;
  const int wm = wid >> 1, wn = wid & 1;
  const int l15 = lane & 15, lhi = lane >> 4;
  const int bm0 = blockIdx.y * 64;
  const int n0 = blockIdx.x * BN;

  // stage A: 64 rows x 256 B (full K)
#pragma unroll
  for (int c = 0; c < 4; c++) {
    int o = c * 4096 + tid * 16;
    int row = o >> 8;
    int scol = ((o & 255) ^ ((row & 7) << 4)) >> 1;
    int gr = bm0 + row;
    gr = gr < N ? gr : N - 1;
    gload_lds16(A + (size_t)gr * 128 + scol, (char*)As + o);
  }
  // stage B: BN rows x 256 B
#pragma unroll
  for (int c = 0; c < BN / 16; c++) {
    int o = c * 4096 + tid * 16;
    int n = o >> 8;
    int scol = ((o & 255) ^ ((n & 7) << 4)) >> 1;
    gload_lds16(Bt + (size_t)(n0 + n) * 128 + scol, (char*)Bs + o);
  }
  asm volatile("s_waitcnt vmcnt(0)" ::: "memory");
  __syncthreads();

  f32x4 acc[FM][FN];
#pragma unroll
  for (int i = 0; i < FM; i++)
#pragma unroll
    for (int j = 0; j < FN; j++) acc[i][j] = (f32x4){0.f, 0.f, 0.f, 0.f};

#pragma unroll
  for (int ks = 0; ks < 4; ks++) {
    short8 af[FM], bf[FN];
#pragma unroll
    for (int fm = 0; fm < FM; fm++) {
      int row = wm * 32 + fm * 16 + l15;
      af[fm] = *(const short8*)((const char*)As + row * 256 +
                                ((ks * 64 + lhi * 16) ^ ((row & 7) << 4)));
    }
#pragma unroll
    for (int fn = 0; fn < FN; fn++) {
      int n = wn * (BN / 2) + fn * 16 + l15;
      bf[fn] = *(const short8*)((const char*)Bs + n * 256 +
                                ((ks * 64 + lhi * 16) ^ ((n & 7) << 4)));
    }
#pragma unroll
    for (int fm = 0; fm < FM; fm++)
#pragma unroll
      for (int fn = 0; fn < FN; fn++)
        acc[fm][fn] = __builtin_amdgcn_mfma_f32_16x16x32_bf16(
            af[fm], bf[fn], acc[fm][fn], 0, 0, 0);
  }

#pragma unroll
  for (int fm = 0; fm < FM; fm++) {
#pragma unroll
    for (int fn = 0; fn < FN; fn++) {
      int col = n0 + wn * (BN / 2) + fn * 16 + l15;
#pragma unroll
      for (int i = 0; i < 4; i++) {
        int row = bm0 + wm * 32 + fm * 16 + lhi * 4 + i;
        if (row < N) {
          Cout[(size_t)row * NC + col] = f2bf(acc[fm][fn][i]);
        }
      }
    }
  }
}

// ---------------- agg-finish layer 1: flat per-edge loop, per-edge norm ----------
// h[d] = relu( xs[d,1024:1152] + b1 + sum_e xs[src_e, r_e*128 + c] * nrm[d*8+r_e] )

__global__ __launch_bounds__(256) void agg_finish1(
    const unsigned short* __restrict__ xs,  // [N][1152] bf16
    const int* __restrict__ row_off,        // [8N+1]
    const int* __restrict__ epack,          // [E] src | rel<<20
    const float* __restrict__ nrm,          // [8N]
    const float* __restrict__ b1,           // [128]
    unsigned short* __restrict__ h,         // [N][128] bf16 out (relu'd)
    int N) {
  int wid = (int)((blockIdx.x * blockDim.x + threadIdx.x) >> 6);
  if (wid >= N) return;
  int lane = threadIdx.x & 63;
  int lo2 = lane * 2;
  unsigned int own = *(const unsigned int*)(xs + (size_t)wid * 1152 + 1024 + lo2);
  float acc0 = bf2f((unsigned short)(own & 0xFFFF)) + b1[lo2];
  float acc1 = bf2f((unsigned short)(own >> 16)) + b1[lo2 + 1];
  int kb = wid * NRELS;
  int b = row_off[kb], e = row_off[kb + NRELS];
  int i = b;
  for (; i + 3 < e; i += 4) {
    int p0 = epack[i], p1 = epack[i + 1], p2 = epack[i + 2], p3 = epack[i + 3];
    unsigned int u0 = *(const unsigned int*)(xs + (size_t)(p0 & 0xFFFFF) * 1152 + ((p0 >> 20) << 7) + lo2);
    unsigned int u1 = *(const unsigned int*)(xs + (size_t)(p1 & 0xFFFFF) * 1152 + ((p1 >> 20) << 7) + lo2);
    unsigned int u2 = *(const unsigned int*)(xs + (size_t)(p2 & 0xFFFFF) * 1152 + ((p2 >> 20) << 7) + lo2);
    unsigned int u3 = *(const unsigned int*)(xs + (size_t)(p3 & 0xFFFFF) * 1152 + ((p3 >> 20) << 7) + lo2);
    float n0 = nrm[kb + (p0 >> 20)], n1 = nrm[kb + (p1 >> 20)];
    float n2 = nrm[kb + (p2 >> 20)], n3 = nrm[kb + (p3 >> 20)];
    acc0 += bf2f((unsigned short)(u0 & 0xFFFF)) * n0 + bf2f((unsigned short)(u1 & 0xFFFF)) * n1 +
            bf2f((unsigned short)(u2 & 0xFFFF)) * n2 + bf2f((unsigned short)(u3 & 0xFFFF)) * n3;
    acc1 += bf2f((unsigned short)(u0 >> 16)) * n0 + bf2f((unsigned short)(u1 >> 16)) * n1 +
            bf2f((unsigned short)(u2 >> 16)) * n2 + bf2f((unsigned short)(u3 >> 16)) * n3;
  }
  for (; i < e; i++) {
    int p = epack[i];
    unsigned int u = *(const unsigned int*)(xs + (size_t)(p & 0xFFFFF) * 1152 + ((p >> 20) << 7) + lo2);
    float nv = nrm[kb + (p >> 20)];
    acc0 += bf2f((unsigned short)(u & 0xFFFF)) * nv;
    acc1 += bf2f((unsigned short)(u >> 16)) * nv;
  }
  unsigned int o = (unsigned int)f2bf(fmaxf(acc0, 0.f)) |
                   ((unsigned int)f2bf(fmaxf(acc1, 0.f)) << 16);
  *(unsigned int*)(h + (size_t)wid * 128 + lo2) = o;
}

// ---------------- agg-finish layer 2: flat per-edge loop (64 cols, fp32 out) ------

__global__ __launch_bounds__(256) void agg_finish2(
    const unsigned short* __restrict__ ys,  // [N][576] bf16
    const int* __restrict__ row_off,        // [8N+1]
    const int* __restrict__ epack,          // [E] src | rel<<20
    const float* __restrict__ nrm,          // [8N]
    const float* __restrict__ b2,           // [64]
    float* __restrict__ outp,               // [N][64] fp32
    int N) {
  int wid = (int)((blockIdx.x * blockDim.x + threadIdx.x) >> 6);
  if (wid >= N) return;
  int col = threadIdx.x & 63;
  float acc = bf2f(ys[(size_t)wid * 576 + 512 + col]) + b2[col];
  int kb = wid * NRELS;
  int b = row_off[kb], e = row_off[kb + NRELS];
  int i = b;
  for (; i + 3 < e; i += 4) {
    int p0 = epack[i], p1 = epack[i + 1], p2 = epack[i + 2], p3 = epack[i + 3];
    float v0 = bf2f(ys[(size_t)(p0 & 0xFFFFF) * 576 + ((p0 >> 20) << 6) + col]);
    float v1 = bf2f(ys[(size_t)(p1 & 0xFFFFF) * 576 + ((p1 >> 20) << 6) + col]);
    float v2 = bf2f(ys[(size_t)(p2 & 0xFFFFF) * 576 + ((p2 >> 20) << 6) + col]);
    float v3 = bf2f(ys[(size_t)(p3 & 0xFFFFF) * 576 + ((p3 >> 20) << 6) + col]);
    acc += v0 * nrm[kb + (p0 >> 20)] + v1 * nrm[kb + (p1 >> 20)] +
           v2 * nrm[kb + (p2 >> 20)] + v3 * nrm[kb + (p3 >> 20)];
  }
  for (; i < e; i++) {
    int p = epack[i];
    acc += bf2f(ys[(size_t)(p & 0xFFFFF) * 576 + ((p >> 20) << 6) + col]) * nrm[kb + (p >> 20)];
  }
  outp[(size_t)wid * 64 + col] = acc;
}

// ---------------- launch ----------------

extern "C" void kernel_launch(void* const* d_in, const int* in_sizes, int n_in,
                              void* d_out, int out_size, void* d_ws, size_t ws_size,
                              hipStream_t stream) {
  const float* x     = (const float*)d_in[0];
  const int*   eidx  = (const int*)d_in[1];
  const int*   et    = (const int*)d_in[2];
  const float* W1    = (const float*)d_in[3];
  const float* root1 = (const float*)d_in[4];
  const float* b1    = (const float*)d_in[5];
  const float* W2    = (const float*)d_in[6];
  const float* root2 = (const float*)d_in[7];
  const float* b2    = (const float*)d_in[8];
  float* out = (float*)d_out;

  const int IN = 128;
  const int N = in_sizes[0] / IN;
  const int E = in_sizes[2];
  const int* src = eidx;
  const int* dst = eidx + E;
  const int M = N * NRELS;            // (dst,rel) key space
  const int NB = (M + 255) / 256;

  auto align = [](size_t v) { return (v + 255) & ~(size_t)255; };
  char* base = (char*)d_ws;
  size_t o = 0;
  int* hist = (int*)(base + o);
  size_t zero_end = (size_t)M * 4;    // memset covers hist only
  o = align(zero_end);
  int* row_off = (int*)(base + o);
  o = align(o + (size_t)(M + 1) * 4);
  int* cursor = (int*)(base + o);
  o = align(o + (size_t)M * 4);
  int* bsum = (int*)(base + o);
  o = align(o + (size_t)(NB + 1) * 4);
  float* nrm = (float*)(base + o);
  o = align(o + (size_t)M * 4);
  int* epack = (int*)(base + o);
  o = align(o + (size_t)E * 4);
  unsigned short* xb = (unsigned short*)(base + o);       // [N][128] bf16
  o = align(o + (size_t)N * 128 * 2);
  unsigned short* hb = (unsigned short*)(base + o);       // [N][128] bf16 (relu'd h)
  o = align(o + (size_t)N * 128 * 2);
  unsigned short* Bt1 = (unsigned short*)(base + o);      // [1152][128]
  o = align(o + (size_t)1152 * 128 * 2);
  unsigned short* Bt2 = (unsigned short*)(base + o);      // [576][128]
  o = align(o + (size_t)576 * 128 * 2);
  unsigned short* xs = (unsigned short*)(base + o);       // [N][1152] bf16 (reused as ys)

  hipMemsetAsync(hist, 0, zero_end, stream);

  const int tb = 256;
  hist_kernel<<<(E + tb - 1) / tb, tb, 0, stream>>>(dst, et, E, hist);
  scan1_kernel<<<NB, 256, 0, stream>>>(hist, M, row_off, bsum, nrm);
  scan2_kernel<<<1, 256, 0, stream>>>(bsum, NB);
  scan3_kernel<<<(M + 256) / 256, 256, 0, stream>>>(row_off, cursor, bsum, M, NB);
  bucket_kernel<<<(E + tb - 1) / tb, tb, 0, stream>>>(src, dst, et, E, cursor, epack);
  cvt_x_kernel<<<(N * 128 / 4 + tb - 1) / tb, tb, 0, stream>>>(x, xb, N * 128 / 4);
  cvt_w_kernel<<<((1152 + 576) * 128 + tb - 1) / tb, tb, 0, stream>>>(
      W1, root1, W2, root2, Bt1, Bt2);

  const int agrid = (N + 3) / 4;
  const int gblocks = (N + 63) / 64;

  // layer 1: xs = xb @ Bt1^T ; h = relu(agg(xs) + root-slice + b1)
  {
    dim3 g(1152 / 128, gblocks);
    gemm_xs<128><<<g, 256, 0, stream>>>(xb, Bt1, xs, N, 1152);
  }
  agg_finish1<<<agrid, 256, 0, stream>>>(xs, row_off, epack, nrm, b1, hb, N);

  // layer 2: ys = hb @ Bt2^T ; out = agg(ys) + root-slice + b2
  {
    dim3 g(576 / 64, gblocks);
    gemm_xs<64><<<g, 256, 0, stream>>>(hb, Bt2, xs, N, 576);
  }
  agg_finish2<<<agrid, 256, 0, stream>>>(xs, row_off, epack, nrm, b2, out, N);
}

// Round 11
// 206.767 us; speedup vs baseline: 2.7188x; 1.0164x over previous
//
#include <hip/hip_runtime.h>

#define NRELS 8

typedef __attribute__((ext_vector_type(8))) short short8;
typedef __attribute__((ext_vector_type(4))) float f32x4;

__device__ __forceinline__ unsigned short f2bf(float f) {
  unsigned int u = __float_as_uint(f);
  u += 0x7FFFu + ((u >> 16) & 1u);
  return (unsigned short)(u >> 16);
}
__device__ __forceinline__ float bf2f(unsigned short h) {
  return __uint_as_float(((unsigned int)h) << 16);
}

__device__ __forceinline__ void gload_lds16(const void* g, void* l) {
  __builtin_amdgcn_global_load_lds(
      (const __attribute__((address_space(1))) unsigned int*)g,
      (__attribute__((address_space(3))) unsigned int*)l, 16, 0, 0);
}

// ---------------- zero scratch (hipMemsetAsync's fill kernel costs 39 us) ---------

__global__ __launch_bounds__(256) void zero_kernel(int* __restrict__ p, int n) {
  int i = blockIdx.x * blockDim.x + threadIdx.x;
  if (i < n) p[i] = 0;
}

// ---------------- histogram over (dst,rel) keys ----------------

__global__ __launch_bounds__(256) void hist_kernel(
    const int* __restrict__ dstp, const int* __restrict__ et, int E,
    int* __restrict__ hist) {
  int i = blockIdx.x * blockDim.x + threadIdx.x;
  if (i < E) {
    atomicAdd(&hist[(size_t)dstp[i] * NRELS + et[i]], 1);
  }
}

// ---------------- hierarchical exclusive scan over M = 8N keys + norm table -------

__global__ __launch_bounds__(256) void scan1_kernel(
    const int* __restrict__ hist, int M, int* __restrict__ row_off,
    int* __restrict__ bsum, float* __restrict__ nrm) {
  __shared__ int s[256];
  int t = threadIdx.x;
  int i = blockIdx.x * 256 + t;
  int v = (i < M) ? hist[i] : 0;
  if (i < M) nrm[i] = 1.0f / (float)max(v, 1);
  s[t] = v;
  __syncthreads();
  for (int off = 1; off < 256; off <<= 1) {
    int u = (t >= off) ? s[t - off] : 0;
    __syncthreads();
    s[t] += u;
    __syncthreads();
  }
  if (i < M) row_off[i] = s[t] - v;  // local exclusive
  if (t == 255) bsum[blockIdx.x] = s[255];
}

__global__ __launch_bounds__(256) void scan2_kernel(int* __restrict__ bsum, int NB) {
  __shared__ int s[256];
  int t = threadIdx.x;
  int C = (NB + 255) / 256;
  int b0 = t * C, b1 = min(NB, b0 + C);
  int sum = 0;
  for (int i = b0; i < b1; i++) sum += bsum[i];
  s[t] = sum;
  __syncthreads();
  for (int off = 1; off < 256; off <<= 1) {
    int u = (t >= off) ? s[t - off] : 0;
    __syncthreads();
    s[t] += u;
    __syncthreads();
  }
  int base = (t == 0) ? 0 : s[t - 1];
  for (int i = b0; i < b1; i++) {
    int v = bsum[i];
    bsum[i] = base;
    base += v;
  }
  if (t == 255) bsum[NB] = s[255];
}

__global__ __launch_bounds__(256) void scan3_kernel(
    int* __restrict__ row_off, int* __restrict__ cursor,
    const int* __restrict__ bsum, int M, int NB) {
  int i = blockIdx.x * 256 + threadIdx.x;
  if (i < M) {
    int v = row_off[i] + bsum[i >> 8];
    row_off[i] = v;
    cursor[i] = v;
  } else if (i == M) {
    row_off[M] = bsum[NB];
  }
}

// ---------------- bucket edges by (dst,rel); store src | rel<<20 ----------------

__global__ __launch_bounds__(256) void bucket_kernel(
    const int* __restrict__ src, const int* __restrict__ dstp,
    const int* __restrict__ et, int E, int* __restrict__ cursor,
    int* __restrict__ epack) {
  int i = blockIdx.x * blockDim.x + threadIdx.x;
  if (i < E) {
    int r = et[i];
    int pos = atomicAdd(&cursor[(size_t)dstp[i] * NRELS + r], 1);
    epack[pos] = src[i] | (r << 20);
  }
}

// ---------------- fp32 -> bf16 feature conversion ----------------

__global__ __launch_bounds__(256) void cvt_x_kernel(
    const float* __restrict__ x, unsigned short* __restrict__ xb, int n4) {
  int i = blockIdx.x * blockDim.x + threadIdx.x;
  if (i < n4) {
    float4 v = ((const float4*)x)[i];
    ushort4 o;
    o.x = f2bf(v.x); o.y = f2bf(v.y); o.z = f2bf(v.z); o.w = f2bf(v.w);
    ((ushort4*)xb)[i] = o;
  }
}

// ---- weights -> bf16, transposed to Bt[n][k] (k contiguous, 128 wide) ----

__global__ __launch_bounds__(256) void cvt_w_kernel(
    const float* __restrict__ W1, const float* __restrict__ root1,
    const float* __restrict__ W2, const float* __restrict__ root2,
    unsigned short* __restrict__ Bt1, unsigned short* __restrict__ Bt2) {
  int idx = blockIdx.x * blockDim.x + threadIdx.x;
  const int T1 = 1152 * 128;
  const int T2 = 576 * 128;
  if (idx < T1) {
    int n = idx >> 7, k = idx & 127;
    float v;
    if (n < 1024) {
      int r = n >> 7, c = n & 127;
      v = W1[((size_t)r * 128 + k) * 128 + c];
    } else {
      v = root1[(size_t)k * 128 + (n - 1024)];
    }
    Bt1[idx] = f2bf(v);
  } else if (idx < T1 + T2) {
    int j = idx - T1;
    int n = j >> 7, k = j & 127;
    float v;
    if (n < 512) {
      int r = n >> 6, c = n & 63;
      v = W2[((size_t)r * 128 + k) * 64 + c];
    } else {
      v = root2[(size_t)k * 64 + (n - 512)];
    }
    Bt2[j] = f2bf(v);
  }
}

// ---------------- MFMA GEMM: xs[N,NC] = A[N,128] @ Bt[NC,128]^T (bf16 out) --------
// Each block: stage A-tile once, loop over TILES col-tiles {stage B, MFMA, store}.

template <int BN, int TILES>
__global__ __launch_bounds__(256) void gemm_xs(
    const unsigned short* __restrict__ A,   // [N][128] bf16
    const unsigned short* __restrict__ Bt,  // [NC][128] bf16
    unsigned short* __restrict__ Cout,      // [N][NC] bf16
    int N, int NC) {
  constexpr int FM = 2;
  constexpr int FN = BN / 32;  // 4 (BN=128) or 2 (BN=64)

  __shared__ unsigned short As[64 * 128];   // 16 KB, 256B rows
  __shared__ unsigned short Bs[BN * 128];   // 32/16 KB

  const int tid = threadIdx.x;
  const int lane = tid & 63;
  const int wid = tid >> 6;
  const int wm = wid >> 1, wn = wid & 1;
  const int l15 = lane & 15, lhi = lane >> 4;
  const int bm0 = blockIdx.y * 64;
  const int ng0 = blockIdx.x * BN * TILES;

  // stage A: 64 rows x 256 B (full K) — once
#pragma unroll
  for (int c = 0; c < 4; c++) {
    int o = c * 4096 + tid * 16;
    int row = o >> 8;
    int scol = ((o & 255) ^ ((row & 7) << 4)) >> 1;
    int gr = bm0 + row;
    gr = gr < N ? gr : N - 1;
    gload_lds16(A + (size_t)gr * 128 + scol, (char*)As + o);
  }

  for (int t = 0; t < TILES; t++) {
    const int n0 = ng0 + t * BN;
    if (t) __syncthreads();  // prev tile's Bs reads complete before restage
    // stage B: BN rows x 256 B
#pragma unroll
    for (int c = 0; c < BN / 16; c++) {
      int o = c * 4096 + tid * 16;
      int n = o >> 8;
      int scol = ((o & 255) ^ ((n & 7) << 4)) >> 1;
      gload_lds16(Bt + (size_t)(n0 + n) * 128 + scol, (char*)Bs + o);
    }
    asm volatile("s_waitcnt vmcnt(0)" ::: "memory");
    __syncthreads();

    f32x4 acc[FM][FN];
#pragma unroll
    for (int i = 0; i < FM; i++)
#pragma unroll
      for (int j = 0; j < FN; j++) acc[i][j] = (f32x4){0.f, 0.f, 0.f, 0.f};

#pragma unroll
    for (int ks = 0; ks < 4; ks++) {
      short8 af[FM], bf[FN];
#pragma unroll
      for (int fm = 0; fm < FM; fm++) {
        int row = wm * 32 + fm * 16 + l15;
        af[fm] = *(const short8*)((const char*)As + row * 256 +
                                  ((ks * 64 + lhi * 16) ^ ((row & 7) << 4)));
      }
#pragma unroll
      for (int fn = 0; fn < FN; fn++) {
        int n = wn * (BN / 2) + fn * 16 + l15;
        bf[fn] = *(const short8*)((const char*)Bs + n * 256 +
                                  ((ks * 64 + lhi * 16) ^ ((n & 7) << 4)));
      }
#pragma unroll
      for (int fm = 0; fm < FM; fm++)
#pragma unroll
        for (int fn = 0; fn < FN; fn++)
          acc[fm][fn] = __builtin_amdgcn_mfma_f32_16x16x32_bf16(
              af[fm], bf[fn], acc[fm][fn], 0, 0, 0);
    }

#pragma unroll
    for (int fm = 0; fm < FM; fm++) {
#pragma unroll
      for (int fn = 0; fn < FN; fn++) {
        int col = n0 + wn * (BN / 2) + fn * 16 + l15;
#pragma unroll
        for (int i = 0; i < 4; i++) {
          int row = bm0 + wm * 32 + fm * 16 + lhi * 4 + i;
          if (row < N) {
            Cout[(size_t)row * NC + col] = f2bf(acc[fm][fn][i]);
          }
        }
      }
    }
  }
}

// ---------------- agg-finish layer 1: flat per-edge loop, per-edge norm ----------

__global__ __launch_bounds__(256) void agg_finish1(
    const unsigned short* __restrict__ xs,  // [N][1152] bf16
    const int* __restrict__ row_off,        // [8N+1]
    const int* __restrict__ epack,          // [E] src | rel<<20
    const float* __restrict__ nrm,          // [8N]
    const float* __restrict__ b1,           // [128]
    unsigned short* __restrict__ h,         // [N][128] bf16 out (relu'd)
    int N) {
  int wid = (int)((blockIdx.x * blockDim.x + threadIdx.x) >> 6);
  if (wid >= N) return;
  int lane = threadIdx.x & 63;
  int lo2 = lane * 2;
  unsigned int own = *(const unsigned int*)(xs + (size_t)wid * 1152 + 1024 + lo2);
  float acc0 = bf2f((unsigned short)(own & 0xFFFF)) + b1[lo2];
  float acc1 = bf2f((unsigned short)(own >> 16)) + b1[lo2 + 1];
  int kb = wid * NRELS;
  int b = row_off[kb], e = row_off[kb + NRELS];
  int i = b;
  for (; i + 3 < e; i += 4) {
    int p0 = epack[i], p1 = epack[i + 1], p2 = epack[i + 2], p3 = epack[i + 3];
    unsigned int u0 = *(const unsigned int*)(xs + (size_t)(p0 & 0xFFFFF) * 1152 + ((p0 >> 20) << 7) + lo2);
    unsigned int u1 = *(const unsigned int*)(xs + (size_t)(p1 & 0xFFFFF) * 1152 + ((p1 >> 20) << 7) + lo2);
    unsigned int u2 = *(const unsigned int*)(xs + (size_t)(p2 & 0xFFFFF) * 1152 + ((p2 >> 20) << 7) + lo2);
    unsigned int u3 = *(const unsigned int*)(xs + (size_t)(p3 & 0xFFFFF) * 1152 + ((p3 >> 20) << 7) + lo2);
    float n0 = nrm[kb + (p0 >> 20)], n1 = nrm[kb + (p1 >> 20)];
    float n2 = nrm[kb + (p2 >> 20)], n3 = nrm[kb + (p3 >> 20)];
    acc0 += bf2f((unsigned short)(u0 & 0xFFFF)) * n0 + bf2f((unsigned short)(u1 & 0xFFFF)) * n1 +
            bf2f((unsigned short)(u2 & 0xFFFF)) * n2 + bf2f((unsigned short)(u3 & 0xFFFF)) * n3;
    acc1 += bf2f((unsigned short)(u0 >> 16)) * n0 + bf2f((unsigned short)(u1 >> 16)) * n1 +
            bf2f((unsigned short)(u2 >> 16)) * n2 + bf2f((unsigned short)(u3 >> 16)) * n3;
  }
  for (; i < e; i++) {
    int p = epack[i];
    unsigned int u = *(const unsigned int*)(xs + (size_t)(p & 0xFFFFF) * 1152 + ((p >> 20) << 7) + lo2);
    float nv = nrm[kb + (p >> 20)];
    acc0 += bf2f((unsigned short)(u & 0xFFFF)) * nv;
    acc1 += bf2f((unsigned short)(u >> 16)) * nv;
  }
  unsigned int o = (unsigned int)f2bf(fmaxf(acc0, 0.f)) |
                   ((unsigned int)f2bf(fmaxf(acc1, 0.f)) << 16);
  *(unsigned int*)(h + (size_t)wid * 128 + lo2) = o;
}

// ---------------- agg-finish layer 2: flat per-edge loop (64 cols, fp32 out) ------

__global__ __launch_bounds__(256) void agg_finish2(
    const unsigned short* __restrict__ ys,  // [N][576] bf16
    const int* __restrict__ row_off,        // [8N+1]
    const int* __restrict__ epack,          // [E] src | rel<<20
    const float* __restrict__ nrm,          // [8N]
    const float* __restrict__ b2,           // [64]
    float* __restrict__ outp,               // [N][64] fp32
    int N) {
  int wid = (int)((blockIdx.x * blockDim.x + threadIdx.x) >> 6);
  if (wid >= N) return;
  int col = threadIdx.x & 63;
  float acc = bf2f(ys[(size_t)wid * 576 + 512 + col]) + b2[col];
  int kb = wid * NRELS;
  int b = row_off[kb], e = row_off[kb + NRELS];
  int i = b;
  for (; i + 3 < e; i += 4) {
    int p0 = epack[i], p1 = epack[i + 1], p2 = epack[i + 2], p3 = epack[i + 3];
    float v0 = bf2f(ys[(size_t)(p0 & 0xFFFFF) * 576 + ((p0 >> 20) << 6) + col]);
    float v1 = bf2f(ys[(size_t)(p1 & 0xFFFFF) * 576 + ((p1 >> 20) << 6) + col]);
    float v2 = bf2f(ys[(size_t)(p2 & 0xFFFFF) * 576 + ((p2 >> 20) << 6) + col]);
    float v3 = bf2f(ys[(size_t)(p3 & 0xFFFFF) * 576 + ((p3 >> 20) << 6) + col]);
    acc += v0 * nrm[kb + (p0 >> 20)] + v1 * nrm[kb + (p1 >> 20)] +
           v2 * nrm[kb + (p2 >> 20)] + v3 * nrm[kb + (p3 >> 20)];
  }
  for (; i < e; i++) {
    int p = epack[i];
    acc += bf2f(ys[(size_t)(p & 0xFFFFF) * 576 + ((p >> 20) << 6) + col]) * nrm[kb + (p >> 20)];
  }
  outp[(size_t)wid * 64 + col] = acc;
}

// ---------------- launch ----------------

extern "C" void kernel_launch(void* const* d_in, const int* in_sizes, int n_in,
                              void* d_out, int out_size, void* d_ws, size_t ws_size,
                              hipStream_t stream) {
  const float* x     = (const float*)d_in[0];
  const int*   eidx  = (const int*)d_in[1];
  const int*   et    = (const int*)d_in[2];
  const float* W1    = (const float*)d_in[3];
  const float* root1 = (const float*)d_in[4];
  const float* b1    = (const float*)d_in[5];
  const float* W2    = (const float*)d_in[6];
  const float* root2 = (const float*)d_in[7];
  const float* b2    = (const float*)d_in[8];
  float* out = (float*)d_out;

  const int IN = 128;
  const int N = in_sizes[0] / IN;
  const int E = in_sizes[2];
  const int* src = eidx;
  const int* dst = eidx + E;
  const int M = N * NRELS;            // (dst,rel) key space
  const int NB = (M + 255) / 256;

  auto align = [](size_t v) { return (v + 255) & ~(size_t)255; };
  char* base = (char*)d_ws;
  size_t o = 0;
  int* hist = (int*)(base + o);
  o = align((size_t)M * 4);
  int* row_off = (int*)(base + o);
  o = align(o + (size_t)(M + 1) * 4);
  int* cursor = (int*)(base + o);
  o = align(o + (size_t)M * 4);
  int* bsum = (int*)(base + o);
  o = align(o + (size_t)(NB + 1) * 4);
  float* nrm = (float*)(base + o);
  o = align(o + (size_t)M * 4);
  int* epack = (int*)(base + o);
  o = align(o + (size_t)E * 4);
  unsigned short* xb = (unsigned short*)(base + o);       // [N][128] bf16
  o = align(o + (size_t)N * 128 * 2);
  unsigned short* hb = (unsigned short*)(base + o);       // [N][128] bf16 (relu'd h)
  o = align(o + (size_t)N * 128 * 2);
  unsigned short* Bt1 = (unsigned short*)(base + o);      // [1152][128]
  o = align(o + (size_t)1152 * 128 * 2);
  unsigned short* Bt2 = (unsigned short*)(base + o);      // [576][128]
  o = align(o + (size_t)576 * 128 * 2);
  unsigned short* xs = (unsigned short*)(base + o);       // [N][1152] bf16 (reused as ys)

  const int tb = 256;
  zero_kernel<<<(M + tb - 1) / tb, tb, 0, stream>>>(hist, M);
  hist_kernel<<<(E + tb - 1) / tb, tb, 0, stream>>>(dst, et, E, hist);
  scan1_kernel<<<NB, 256, 0, stream>>>(hist, M, row_off, bsum, nrm);
  scan2_kernel<<<1, 256, 0, stream>>>(bsum, NB);
  scan3_kernel<<<(M + 256) / 256, 256, 0, stream>>>(row_off, cursor, bsum, M, NB);
  bucket_kernel<<<(E + tb - 1) / tb, tb, 0, stream>>>(src, dst, et, E, cursor, epack);
  cvt_x_kernel<<<(N * 128 / 4 + tb - 1) / tb, tb, 0, stream>>>(x, xb, N * 128 / 4);
  cvt_w_kernel<<<((1152 + 576) * 128 + tb - 1) / tb, tb, 0, stream>>>(
      W1, root1, W2, root2, Bt1, Bt2);

  const int agrid = (N + 3) / 4;
  const int gblocks = (N + 63) / 64;

  // layer 1: xs = xb @ Bt1^T ; h = relu(agg(xs) + root-slice + b1)
  {
    dim3 g(3, gblocks);  // 3 col-groups x 3 tiles of 128 = 1152
    gemm_xs<128, 3><<<g, 256, 0, stream>>>(xb, Bt1, xs, N, 1152);
  }
  agg_finish1<<<agrid, 256, 0, stream>>>(xs, row_off, epack, nrm, b1, hb, N);

  // layer 2: ys = hb @ Bt2^T ; out = agg(ys) + root-slice + b2
  {
    dim3 g(3, gblocks);  // 3 col-groups x 3 tiles of 64 = 576
    gemm_xs<64, 3><<<g, 256, 0, stream>>>(hb, Bt2, xs, N, 576);
  }
  agg_finish2<<<agrid, 256, 0, stream>>>(xs, row_off, epack, nrm, b2, out, N);
}